// Round 2
// baseline (1011.704 us; speedup 1.0000x reference)
//
#include <hip/hip_runtime.h>
#include <hip/hip_bf16.h>
#include <stdint.h>
#include <stddef.h>

typedef __bf16 bf16;
typedef __bf16 bf16x4 __attribute__((ext_vector_type(4)));
typedef __bf16 bf16x8 __attribute__((ext_vector_type(8)));
typedef float  f32x4  __attribute__((ext_vector_type(4)));

// async global->LDS, 16B per lane; dst must be wave-uniform base (lane data
// lands at dst + lane*16).
__device__ __forceinline__ void async16(const void* src, void* dst) {
    __builtin_amdgcn_global_load_lds(
        (__attribute__((address_space(1))) void*)(void*)(src),
        (__attribute__((address_space(3))) void*)(dst),
        16, 0, 0);
}

// ---------------------------------------------------------------------------
// Kernel 0: f32 -> bf16 weight conversion (n divisible by 4)
// ---------------------------------------------------------------------------
__global__ __launch_bounds__(256)
void f2b(const float* __restrict__ src, bf16* __restrict__ dst, int n)
{
    const int i = (blockIdx.x * 256 + threadIdx.x) * 4;
    if (i < n) {
        f32x4 c = *(const f32x4*)(src + i);
        bf16x4 o;
        #pragma unroll
        for (int q = 0; q < 4; ++q) o[q] = (bf16)c[q];
        *(bf16x4*)(dst + i) = o;
    }
}

// ---------------------------------------------------------------------------
// Kernel 1: LN over x rows (768, f32 in) + window permutation -> bf16 Y.
// 1 wave per row.
// ---------------------------------------------------------------------------
__global__ __launch_bounds__(256)
void ln1_win(const float* __restrict__ x, const float* __restrict__ g,
             const float* __restrict__ b, bf16* __restrict__ Y)
{
    const int row  = blockIdx.x * 4 + (threadIdx.x >> 6);
    const int lane = threadIdx.x & 63;
    const float* xr = x + (size_t)row * 768;
    float v[12];
    float sum = 0.f, ssq = 0.f;
    #pragma unroll
    for (int j = 0; j < 3; ++j) {
        f32x4 c = *(const f32x4*)(xr + j * 256 + lane * 4);
        #pragma unroll
        for (int q = 0; q < 4; ++q) {
            float f = c[q];
            v[j * 4 + q] = f; sum += f; ssq += f * f;
        }
    }
    #pragma unroll
    for (int d = 1; d < 64; d <<= 1) {
        sum += __shfl_xor(sum, d, 64);
        ssq += __shfl_xor(ssq, d, 64);
    }
    const float mean = sum * (1.f / 768.f);
    const float rstd = rsqrtf(ssq * (1.f / 768.f) - mean * mean + 1e-5f);
    // window permutation: (b, hy, wx) -> window bw, token n
    const int bb = row >> 14;          // row / 16384  (h=w=128)
    const int l  = row & 16383;
    const int hy = l >> 7, wx = l & 127;
    const int m  = ((bb * 256 + (hy >> 3) * 16 + (wx >> 3)) << 6)
                 + ((hy & 7) << 3) + (wx & 7);
    bf16* yr = Y + (size_t)m * 768;
    #pragma unroll
    for (int j = 0; j < 3; ++j) {
        const int c0 = j * 256 + lane * 4;
        f32x4 gg = *(const f32x4*)(g + c0);
        f32x4 bv = *(const f32x4*)(b + c0);
        bf16x4 ov;
        #pragma unroll
        for (int q = 0; q < 4; ++q)
            ov[q] = (bf16)((v[j * 4 + q] - mean) * rstd * gg[q] + bv[q]);
        *(bf16x4*)(yr + c0) = ov;
    }
}

// ---------------------------------------------------------------------------
// GEMM: C = A @ B^T (+bias). 128x128 tile, BK=64, 256 threads (2x2 waves of
// 64x64), mfma_f32_16x16x32_bf16, XOR-swizzled LDS (slot = kc ^ (row&7)).
// AMODE 0: plain A (row stride K).
// AMODE 1: QKV fused gather: nbase<768 -> A = Y[S+g]+Y[2S+g] (VGPR path);
//          else A = Y[g] (async path); g = (m*768+k) mod S.
// ---------------------------------------------------------------------------
template<int AMODE, bool BIAS>
__global__ __launch_bounds__(256, 2)
void gemm_bt(const bf16* __restrict__ A, const bf16* __restrict__ Yg,
             const bf16* __restrict__ Bm, const float* __restrict__ bias,
             bf16* __restrict__ Cm, int K, int ldc, int Smod)
{
    __shared__ bf16 At[128 * 64];
    __shared__ bf16 Bt[128 * 64];

    const int tid  = threadIdx.x;
    const int lane = tid & 63;
    const int w    = tid >> 6;
    const int quad = lane >> 4;
    const int l16  = lane & 15;
    const int wm   = (w >> 1) * 64;
    const int wn   = (w & 1) * 64;
    const int mbase = blockIdx.y * 128;
    const int nbase = blockIdx.x * 128;

    const f32x4 zero = {0.f, 0.f, 0.f, 0.f};
    f32x4 acc[4][4];
    #pragma unroll
    for (int i = 0; i < 4; ++i)
        #pragma unroll
        for (int j = 0; j < 4; ++j) acc[i][j] = zero;

    const bool qpath = (AMODE == 1) && (nbase < 768);

    for (int kb = 0; kb < K; kb += 64) {
        // ---- stage B tile (async, swizzled) ----
        {
            const int rb = 32 * w;
            const int rsub = lane >> 3;
            const int slot = lane & 7;
            #pragma unroll
            for (int t = 0; t < 4; ++t) {
                const int row = rb + 8 * t + rsub;
                const int kc  = slot ^ (row & 7);
                async16(Bm + (size_t)(nbase + row) * K + kb + kc * 8,
                        Bt + (rb + 8 * t) * 64);
            }
        }
        // ---- stage A tile ----
        if (AMODE == 0) {
            const int rb = 32 * w;
            const int rsub = lane >> 3;
            const int slot = lane & 7;
            #pragma unroll
            for (int t = 0; t < 4; ++t) {
                const int row = rb + 8 * t + rsub;
                const int kc  = slot ^ (row & 7);
                async16(A + (size_t)(mbase + row) * K + kb + kc * 8,
                        At + (rb + 8 * t) * 64);
            }
        } else if (qpath) {
            #pragma unroll
            for (int t = 0; t < 4; ++t) {
                const int c    = tid + 256 * t;
                const int row  = c >> 3;
                const int slot = c & 7;
                const int kc   = slot ^ (row & 7);
                int f = (mbase + row) * 768 + kb + kc * 8;
                if (f >= 2 * Smod) f -= 2 * Smod;
                else if (f >= Smod) f -= Smod;
                bf16x8 u = *(const bf16x8*)(Yg + Smod + f);
                bf16x8 vv = *(const bf16x8*)(Yg + 2 * Smod + f);
                bf16x8 r;
                #pragma unroll
                for (int q = 0; q < 8; ++q)
                    r[q] = (bf16)((float)u[q] + (float)vv[q]);
                *(bf16x8*)(At + row * 64 + slot * 8) = r;
            }
        } else {
            const int rb = 32 * w;
            const int rsub = lane >> 3;
            const int slot = lane & 7;
            #pragma unroll
            for (int t = 0; t < 4; ++t) {
                const int row = rb + 8 * t + rsub;
                const int kc  = slot ^ (row & 7);
                int f = (mbase + row) * 768 + kb + kc * 8;
                if (f >= 2 * Smod) f -= 2 * Smod;
                else if (f >= Smod) f -= Smod;
                async16(Yg + f, At + (rb + 8 * t) * 64);
            }
        }
        __syncthreads();

        #pragma unroll
        for (int ks = 0; ks < 2; ++ks) {
            bf16x8 af[4], bfr[4];
            #pragma unroll
            for (int i = 0; i < 4; ++i) {
                const int row  = wm + 16 * i + l16;
                const int slot = (ks * 4 + quad) ^ (row & 7);
                af[i] = *(const bf16x8*)(At + row * 64 + slot * 8);
            }
            #pragma unroll
            for (int j = 0; j < 4; ++j) {
                const int row  = wn + 16 * j + l16;
                const int slot = (ks * 4 + quad) ^ (row & 7);
                bfr[j] = *(const bf16x8*)(Bt + row * 64 + slot * 8);
            }
            #pragma unroll
            for (int i = 0; i < 4; ++i)
                #pragma unroll
                for (int j = 0; j < 4; ++j)
                    acc[i][j] = __builtin_amdgcn_mfma_f32_16x16x32_bf16(
                        af[i], bfr[j], acc[i][j], 0, 0, 0);
        }
        __syncthreads();
    }

    // epilogue: C/D layout col=lane&15, row=quad*4+reg
    #pragma unroll
    for (int i = 0; i < 4; ++i) {
        const int row0 = mbase + wm + 16 * i + quad * 4;
        #pragma unroll
        for (int j = 0; j < 4; ++j) {
            const int col = nbase + wn + 16 * j + l16;
            float bv = 0.f;
            if (BIAS) bv = bias[col];
            #pragma unroll
            for (int r = 0; r < 4; ++r)
                Cm[(size_t)(row0 + r) * ldc + col] = (bf16)(acc[i][j][r] + bv);
        }
    }
}

// ---------------------------------------------------------------------------
// Kernel 3: windowed attention, one wave per (window, head). 64x64 tiles.
// QKV layout: row m = bw*64+token, cols [0,768) Q, [768,1536) K, [1536,2304) V.
// ---------------------------------------------------------------------------
__global__ __launch_bounds__(64)
void attn_win(const bf16* __restrict__ QKV, bf16* __restrict__ AOut)
{
    const int blk  = blockIdx.x;
    const int bw   = blk / 12;
    const int h    = blk % 12;
    const int lane = threadIdx.x;
    const int quad = lane >> 4;
    const int l16  = lane & 15;

    __shared__ bf16 Kt[64 * 64];   // K (swizzled), later reused for P
    __shared__ bf16 Vt[64 * 64];   // V row-major [k][n]

    const size_t rowbase = (size_t)bw * 64;

    // stage K (swizzled slots) and V (natural slots)
    {
        const int rsub = lane >> 3;
        const int slot = lane & 7;
        #pragma unroll
        for (int t = 0; t < 8; ++t) {
            const int row = 8 * t + rsub;
            const int kcK = slot ^ (row & 7);
            async16(QKV + (rowbase + row) * 2304 + 768 + h * 64 + kcK * 8,
                    Kt + (8 * t) * 64);
            async16(QKV + (rowbase + row) * 2304 + 1536 + h * 64 + slot * 8,
                    Vt + (8 * t) * 64);
        }
    }

    // Q fragments straight from global
    bf16x8 qf[4][2];
    #pragma unroll
    for (int i = 0; i < 4; ++i)
        #pragma unroll
        for (int ks = 0; ks < 2; ++ks)
            qf[i][ks] = *(const bf16x8*)(QKV + (rowbase + 16 * i + l16) * 2304
                                         + h * 64 + ks * 32 + quad * 8);
    __syncthreads();

    const f32x4 zero = {0.f, 0.f, 0.f, 0.f};
    f32x4 s[4][4];
    #pragma unroll
    for (int i = 0; i < 4; ++i)
        #pragma unroll
        for (int j = 0; j < 4; ++j) s[i][j] = zero;

    #pragma unroll
    for (int ks = 0; ks < 2; ++ks) {
        bf16x8 kf[4];
        #pragma unroll
        for (int j = 0; j < 4; ++j) {
            const int row  = 16 * j + l16;
            const int slot = (ks * 4 + quad) ^ (row & 7);
            kf[j] = *(const bf16x8*)(Kt + row * 64 + slot * 8);
        }
        #pragma unroll
        for (int i = 0; i < 4; ++i)
            #pragma unroll
            for (int j = 0; j < 4; ++j)
                s[i][j] = __builtin_amdgcn_mfma_f32_16x16x32_bf16(
                    qf[i][ks], kf[j], s[i][j], 0, 0, 0);
    }

    // softmax over rows (row = 16*i + quad*4 + r; cols spread over 16 lanes x 4 j)
    float rrec[4][4];
    #pragma unroll
    for (int i = 0; i < 4; ++i) {
        #pragma unroll
        for (int r = 0; r < 4; ++r) {
            float mx = s[i][0][r];
            #pragma unroll
            for (int j = 1; j < 4; ++j) mx = fmaxf(mx, s[i][j][r]);
            #pragma unroll
            for (int d = 1; d < 16; d <<= 1) mx = fmaxf(mx, __shfl_xor(mx, d, 64));
            float sum = 0.f;
            #pragma unroll
            for (int j = 0; j < 4; ++j) {
                float p = __expf((s[i][j][r] - mx) * 0.125f);
                s[i][j][r] = p;
                sum += p;
            }
            #pragma unroll
            for (int d = 1; d < 16; d <<= 1) sum += __shfl_xor(sum, d, 64);
            rrec[i][r] = 1.f / sum;
        }
    }

    // P (unnormalized exp) -> LDS (reuse Kt), swizzled, bf16
    #pragma unroll
    for (int i = 0; i < 4; ++i)
        #pragma unroll
        for (int j = 0; j < 4; ++j)
            #pragma unroll
            for (int r = 0; r < 4; ++r) {
                const int row  = 16 * i + quad * 4 + r;
                const int col  = 16 * j + l16;
                const int slot = (col >> 3) ^ (row & 7);
                Kt[row * 64 + slot * 8 + (col & 7)] = (bf16)s[i][j][r];
            }
    __syncthreads();

    // O = P @ V
    f32x4 o[4][4];
    #pragma unroll
    for (int i = 0; i < 4; ++i)
        #pragma unroll
        for (int j = 0; j < 4; ++j) o[i][j] = zero;

    #pragma unroll
    for (int ks = 0; ks < 2; ++ks) {
        bf16x8 pf[4], vf[4];
        #pragma unroll
        for (int i = 0; i < 4; ++i) {
            const int row  = 16 * i + l16;
            const int slot = (ks * 4 + quad) ^ (row & 7);
            pf[i] = *(const bf16x8*)(Kt + row * 64 + slot * 8);
        }
        #pragma unroll
        for (int j = 0; j < 4; ++j) {
            bf16x8 t;
            #pragma unroll
            for (int q = 0; q < 8; ++q)
                t[q] = Vt[(ks * 32 + quad * 8 + q) * 64 + 16 * j + l16];
            vf[j] = t;
        }
        #pragma unroll
        for (int i = 0; i < 4; ++i)
            #pragma unroll
            for (int j = 0; j < 4; ++j)
                o[i][j] = __builtin_amdgcn_mfma_f32_16x16x32_bf16(
                    pf[i], vf[j], o[i][j], 0, 0, 0);
    }

    #pragma unroll
    for (int i = 0; i < 4; ++i)
        #pragma unroll
        for (int j = 0; j < 4; ++j)
            #pragma unroll
            for (int r = 0; r < 4; ++r) {
                const size_t grow = rowbase + 16 * i + quad * 4 + r;
                const int col = h * 64 + 16 * j + l16;
                AOut[grow * 768 + col] = (bf16)(o[i][j][r] * rrec[i][r]);
            }
}

// ---------------------------------------------------------------------------
// Kernel 5: LN2 + fc1 (C->1) + exact gelu + fc2 (1->C). 1 wave per row.
// f32 weights, f32 output.
// ---------------------------------------------------------------------------
__global__ __launch_bounds__(256)
void final_fused(const bf16* __restrict__ P, const float* __restrict__ g2,
                 const float* __restrict__ b2, const float* __restrict__ fc1w,
                 const float* __restrict__ fc1b, const float* __restrict__ fc2w,
                 const float* __restrict__ fc2b, float* __restrict__ out)
{
    const int row  = blockIdx.x * 4 + (threadIdx.x >> 6);
    const int lane = threadIdx.x & 63;
    const bf16* pr = P + (size_t)row * 768;
    float v[12];
    float sum = 0.f, ssq = 0.f;
    #pragma unroll
    for (int j = 0; j < 3; ++j) {
        bf16x4 c = *(const bf16x4*)(pr + j * 256 + lane * 4);
        #pragma unroll
        for (int q = 0; q < 4; ++q) {
            float f = (float)c[q];
            v[j * 4 + q] = f; sum += f; ssq += f * f;
        }
    }
    #pragma unroll
    for (int d = 1; d < 64; d <<= 1) {
        sum += __shfl_xor(sum, d, 64);
        ssq += __shfl_xor(ssq, d, 64);
    }
    const float mean = sum * (1.f / 768.f);
    const float rstd = rsqrtf(ssq * (1.f / 768.f) - mean * mean + 1e-5f);
    float part = 0.f;
    #pragma unroll
    for (int j = 0; j < 3; ++j) {
        const int c0 = j * 256 + lane * 4;
        f32x4 gg = *(const f32x4*)(g2 + c0);
        f32x4 bb = *(const f32x4*)(b2 + c0);
        f32x4 f1 = *(const f32x4*)(fc1w + c0);
        #pragma unroll
        for (int q = 0; q < 4; ++q) {
            float ln = (v[j * 4 + q] - mean) * rstd * gg[q] + bb[q];
            part += ln * f1[q];
        }
    }
    #pragma unroll
    for (int d = 1; d < 64; d <<= 1) part += __shfl_xor(part, d, 64);
    const float sv = part + fc1b[0];
    const float ge = 0.5f * sv * (1.f + erff(sv * 0.70710678118654752f));
    float* orow = out + (size_t)row * 768;
    #pragma unroll
    for (int j = 0; j < 3; ++j) {
        const int c0 = j * 256 + lane * 4;
        f32x4 f2  = *(const f32x4*)(fc2w + c0);
        f32x4 b2v = *(const f32x4*)(fc2b + c0);
        f32x4 ov;
        #pragma unroll
        for (int q = 0; q < 4; ++q)
            ov[q] = ge * f2[q] + b2v[q];
        *(f32x4*)(orow + c0) = ov;
    }
}

// ---------------------------------------------------------------------------
extern "C" void kernel_launch(void* const* d_in, const int* in_sizes, int n_in,
                              void* d_out, int out_size, void* d_ws, size_t ws_size,
                              hipStream_t stream)
{
    const float* x     = (const float*)d_in[0];
    const float* n1g   = (const float*)d_in[1];
    const float* n1b   = (const float*)d_in[2];
    const float* n2g   = (const float*)d_in[3];
    const float* n2b   = (const float*)d_in[4];
    const float* qkvw  = (const float*)d_in[5];
    const float* projw = (const float*)d_in[6];
    const float* projb = (const float*)d_in[7];
    const float* fc1w  = (const float*)d_in[8];
    const float* fc1b  = (const float*)d_in[9];
    const float* fc2w  = (const float*)d_in[10];
    const float* fc2b  = (const float*)d_in[11];
    float* out = (float*)d_out;

    const int total = in_sizes[0];          // B * 16384 * 768
    const int rows  = total / 768;          // 65536 token rows
    const int Smod  = total / 3;            // 2^24 for B=4
    const int Bw    = rows / 64;            // windows
    const int C     = 768;

    // ws layout (bf16): [QKV: rows*2304] [Y/AOut: rows*768]
    //                   [qkvw_b: 2304*768] [projw_b: 768*768]; P reuses QKV.
    bf16* qkv    = (bf16*)d_ws;
    bf16* Ybuf   = qkv + (size_t)rows * 2304;
    bf16* qkvw_b = Ybuf + (size_t)rows * 768;
    bf16* projw_b = qkvw_b + (size_t)3 * C * C;
    bf16* Pbuf   = qkv;

    const int nqkvw = 3 * C * C;   // 1769472
    const int nprojw = C * C;      // 589824
    f2b<<<(nqkvw / 4 + 255) / 256, 256, 0, stream>>>(qkvw, qkvw_b, nqkvw);
    f2b<<<(nprojw / 4 + 255) / 256, 256, 0, stream>>>(projw, projw_b, nprojw);

    ln1_win<<<rows / 4, 256, 0, stream>>>(x, n1g, n1b, Ybuf);

    gemm_bt<1, false><<<dim3(2304 / 128, rows / 128), 256, 0, stream>>>(
        nullptr, Ybuf, qkvw_b, nullptr, qkv, 768, 2304, Smod);

    attn_win<<<Bw * 12, 64, 0, stream>>>(qkv, Ybuf);   // AOut overwrites dead Y

    gemm_bt<0, true><<<dim3(768 / 128, rows / 128), 256, 0, stream>>>(
        Ybuf, nullptr, projw_b, projb, Pbuf, 768, 768, 0);

    final_fused<<<rows / 4, 256, 0, stream>>>(Pbuf, n2g, n2b, fc1w, fc1b,
                                              fc2w, fc2b, out);
}

// Round 3
// 856.382 us; speedup vs baseline: 1.1814x; 1.1814x over previous
//
#include <hip/hip_runtime.h>
#include <hip/hip_bf16.h>
#include <stdint.h>
#include <stddef.h>

typedef __bf16 bf16;
typedef __bf16 bf16x4 __attribute__((ext_vector_type(4)));
typedef __bf16 bf16x8 __attribute__((ext_vector_type(8)));
typedef float  f32x4  __attribute__((ext_vector_type(4)));

__device__ __forceinline__ void async16(const void* src, void* dst) {
    __builtin_amdgcn_global_load_lds(
        (__attribute__((address_space(1))) void*)(void*)(src),
        (__attribute__((address_space(3))) void*)(dst),
        16, 0, 0);
}

// ---------------------------------------------------------------------------
// Kernel 0: f32 -> bf16 weight conversion (n divisible by 4)
// ---------------------------------------------------------------------------
__global__ __launch_bounds__(256)
void f2b(const float* __restrict__ src, bf16* __restrict__ dst, int n)
{
    const int i = (blockIdx.x * 256 + threadIdx.x) * 4;
    if (i < n) {
        f32x4 c = *(const f32x4*)(src + i);
        bf16x4 o;
        #pragma unroll
        for (int q = 0; q < 4; ++q) o[q] = (bf16)c[q];
        *(bf16x4*)(dst + i) = o;
    }
}

// ---------------------------------------------------------------------------
// Kernel 1: LN over x rows (768, f32 in) + window permutation -> bf16 Y.
// ---------------------------------------------------------------------------
__global__ __launch_bounds__(256)
void ln1_win(const float* __restrict__ x, const float* __restrict__ g,
             const float* __restrict__ b, bf16* __restrict__ Y)
{
    const int row  = blockIdx.x * 4 + (threadIdx.x >> 6);
    const int lane = threadIdx.x & 63;
    const float* xr = x + (size_t)row * 768;
    float v[12];
    float sum = 0.f, ssq = 0.f;
    #pragma unroll
    for (int j = 0; j < 3; ++j) {
        f32x4 c = *(const f32x4*)(xr + j * 256 + lane * 4);
        #pragma unroll
        for (int q = 0; q < 4; ++q) {
            float f = c[q];
            v[j * 4 + q] = f; sum += f; ssq += f * f;
        }
    }
    #pragma unroll
    for (int d = 1; d < 64; d <<= 1) {
        sum += __shfl_xor(sum, d, 64);
        ssq += __shfl_xor(ssq, d, 64);
    }
    const float mean = sum * (1.f / 768.f);
    const float rstd = rsqrtf(ssq * (1.f / 768.f) - mean * mean + 1e-5f);
    const int bb = row >> 14;
    const int l  = row & 16383;
    const int hy = l >> 7, wx = l & 127;
    const int m  = ((bb * 256 + (hy >> 3) * 16 + (wx >> 3)) << 6)
                 + ((hy & 7) << 3) + (wx & 7);
    bf16* yr = Y + (size_t)m * 768;
    #pragma unroll
    for (int j = 0; j < 3; ++j) {
        const int c0 = j * 256 + lane * 4;
        f32x4 gg = *(const f32x4*)(g + c0);
        f32x4 bv = *(const f32x4*)(b + c0);
        bf16x4 ov;
        #pragma unroll
        for (int q = 0; q < 4; ++q)
            ov[q] = (bf16)((v[j * 4 + q] - mean) * rstd * gg[q] + bv[q]);
        *(bf16x4*)(yr + c0) = ov;
    }
}

// ---------------------------------------------------------------------------
// GEMM: C = A @ B^T (+bias). 128(M)x256(N) tile, BK=64, 256 threads
// (2x2 waves, each 64x128), mfma_f32_16x16x32_bf16, XOR-swizzled LDS.
// 1D grid + XCD-aware swizzle: bid&7 = XCD (round-robin dispatch assumption,
// perf-only); each XCD gets a contiguous mbase chunk, nbase fastest, so all
// blocks sharing an A-stripe run on one XCD -> A re-reads hit its L2.
// AMODE 0: plain A. AMODE 1: QKV gather (nbase<768 -> green+blue VGPR path,
// else red async path); g = (m*768+k) mod Smod.
// ---------------------------------------------------------------------------
template<int AMODE, bool BIAS>
__global__ __launch_bounds__(256, 2)
void gemm_bt(const bf16* __restrict__ A, const bf16* __restrict__ Yg,
             const bf16* __restrict__ Bm, const float* __restrict__ bias,
             bf16* __restrict__ Cm, int K, int ldc, int Smod, int nb_n)
{
    __shared__ bf16 At[128 * 64];
    __shared__ bf16 Bt[256 * 64];

    const int per    = gridDim.x >> 3;
    const int mchunk = per / nb_n;
    const int xcd    = blockIdx.x & 7;
    const int slot_b = blockIdx.x >> 3;
    const int mbase  = (xcd * mchunk + slot_b / nb_n) * 128;
    const int nbase  = (slot_b % nb_n) * 256;

    const int tid  = threadIdx.x;
    const int lane = tid & 63;
    const int w    = tid >> 6;
    const int quad = lane >> 4;
    const int l16  = lane & 15;
    const int wm   = (w >> 1) * 64;
    const int wn   = (w & 1) * 128;

    const f32x4 zero = {0.f, 0.f, 0.f, 0.f};
    f32x4 acc[4][8];
    #pragma unroll
    for (int i = 0; i < 4; ++i)
        #pragma unroll
        for (int j = 0; j < 8; ++j) acc[i][j] = zero;

    const bool qpath = (AMODE == 1) && (nbase < 768);

    for (int kb = 0; kb < K; kb += 64) {
        // ---- stage B tile: 256 rows x 64 ----
        {
            const int rb   = 64 * w;
            const int rsub = lane >> 3;
            const int slot = lane & 7;
            #pragma unroll
            for (int t = 0; t < 8; ++t) {
                const int row = rb + 8 * t + rsub;
                const int kc  = slot ^ (row & 7);
                async16(Bm + (size_t)(nbase + row) * K + kb + kc * 8,
                        Bt + (rb + 8 * t) * 64);
            }
        }
        // ---- stage A tile: 128 rows x 64 ----
        if (AMODE == 0) {
            const int rb   = 32 * w;
            const int rsub = lane >> 3;
            const int slot = lane & 7;
            #pragma unroll
            for (int t = 0; t < 4; ++t) {
                const int row = rb + 8 * t + rsub;
                const int kc  = slot ^ (row & 7);
                async16(A + (size_t)(mbase + row) * K + kb + kc * 8,
                        At + (rb + 8 * t) * 64);
            }
        } else if (qpath) {
            #pragma unroll
            for (int t = 0; t < 4; ++t) {
                const int c    = tid + 256 * t;
                const int row  = c >> 3;
                const int slot = c & 7;
                const int kc   = slot ^ (row & 7);
                int f = (mbase + row) * 768 + kb + kc * 8;
                if (f >= 2 * Smod) f -= 2 * Smod;
                else if (f >= Smod) f -= Smod;
                bf16x8 u  = *(const bf16x8*)(Yg + Smod + f);
                bf16x8 vv = *(const bf16x8*)(Yg + 2 * Smod + f);
                bf16x8 r;
                #pragma unroll
                for (int q = 0; q < 8; ++q)
                    r[q] = (bf16)((float)u[q] + (float)vv[q]);
                *(bf16x8*)(At + row * 64 + slot * 8) = r;
            }
        } else {
            const int rb   = 32 * w;
            const int rsub = lane >> 3;
            const int slot = lane & 7;
            #pragma unroll
            for (int t = 0; t < 4; ++t) {
                const int row = rb + 8 * t + rsub;
                const int kc  = slot ^ (row & 7);
                int f = (mbase + row) * 768 + kb + kc * 8;
                if (f >= 2 * Smod) f -= 2 * Smod;
                else if (f >= Smod) f -= Smod;
                async16(Yg + f, At + (rb + 8 * t) * 64);
            }
        }
        __syncthreads();

        #pragma unroll
        for (int ks = 0; ks < 2; ++ks) {
            bf16x8 af[4], bfr[8];
            #pragma unroll
            for (int i = 0; i < 4; ++i) {
                const int row  = wm + 16 * i + l16;
                const int slot = (ks * 4 + quad) ^ (row & 7);
                af[i] = *(const bf16x8*)(At + row * 64 + slot * 8);
            }
            #pragma unroll
            for (int j = 0; j < 8; ++j) {
                const int row  = wn + 16 * j + l16;
                const int slot = (ks * 4 + quad) ^ (row & 7);
                bfr[j] = *(const bf16x8*)(Bt + row * 64 + slot * 8);
            }
            #pragma unroll
            for (int i = 0; i < 4; ++i)
                #pragma unroll
                for (int j = 0; j < 8; ++j)
                    acc[i][j] = __builtin_amdgcn_mfma_f32_16x16x32_bf16(
                        af[i], bfr[j], acc[i][j], 0, 0, 0);
        }
        __syncthreads();
    }

    // epilogue: C/D layout col=lane&15, row=quad*4+reg
    #pragma unroll
    for (int i = 0; i < 4; ++i) {
        const int row0 = mbase + wm + 16 * i + quad * 4;
        #pragma unroll
        for (int j = 0; j < 8; ++j) {
            const int col = nbase + wn + 16 * j + l16;
            float bv = 0.f;
            if (BIAS) bv = bias[col];
            #pragma unroll
            for (int r = 0; r < 4; ++r)
                Cm[(size_t)(row0 + r) * ldc + col] = (bf16)(acc[i][j][r] + bv);
        }
    }
}

// ---------------------------------------------------------------------------
// Kernel 3: windowed attention, one wave per (window, head). 64x64 tiles.
// ---------------------------------------------------------------------------
__global__ __launch_bounds__(64)
void attn_win(const bf16* __restrict__ QKV, bf16* __restrict__ AOut)
{
    const int blk  = blockIdx.x;
    const int bw   = blk / 12;
    const int h    = blk % 12;
    const int lane = threadIdx.x;
    const int quad = lane >> 4;
    const int l16  = lane & 15;

    __shared__ bf16 Kt[64 * 64];
    __shared__ bf16 Vt[64 * 64];

    const size_t rowbase = (size_t)bw * 64;

    {
        const int rsub = lane >> 3;
        const int slot = lane & 7;
        #pragma unroll
        for (int t = 0; t < 8; ++t) {
            const int row = 8 * t + rsub;
            const int kcK = slot ^ (row & 7);
            async16(QKV + (rowbase + row) * 2304 + 768 + h * 64 + kcK * 8,
                    Kt + (8 * t) * 64);
            async16(QKV + (rowbase + row) * 2304 + 1536 + h * 64 + slot * 8,
                    Vt + (8 * t) * 64);
        }
    }

    bf16x8 qf[4][2];
    #pragma unroll
    for (int i = 0; i < 4; ++i)
        #pragma unroll
        for (int ks = 0; ks < 2; ++ks)
            qf[i][ks] = *(const bf16x8*)(QKV + (rowbase + 16 * i + l16) * 2304
                                         + h * 64 + ks * 32 + quad * 8);
    __syncthreads();

    const f32x4 zero = {0.f, 0.f, 0.f, 0.f};
    f32x4 s[4][4];
    #pragma unroll
    for (int i = 0; i < 4; ++i)
        #pragma unroll
        for (int j = 0; j < 4; ++j) s[i][j] = zero;

    #pragma unroll
    for (int ks = 0; ks < 2; ++ks) {
        bf16x8 kf[4];
        #pragma unroll
        for (int j = 0; j < 4; ++j) {
            const int row  = 16 * j + l16;
            const int slot = (ks * 4 + quad) ^ (row & 7);
            kf[j] = *(const bf16x8*)(Kt + row * 64 + slot * 8);
        }
        #pragma unroll
        for (int i = 0; i < 4; ++i)
            #pragma unroll
            for (int j = 0; j < 4; ++j)
                s[i][j] = __builtin_amdgcn_mfma_f32_16x16x32_bf16(
                    qf[i][ks], kf[j], s[i][j], 0, 0, 0);
    }

    float rrec[4][4];
    #pragma unroll
    for (int i = 0; i < 4; ++i) {
        #pragma unroll
        for (int r = 0; r < 4; ++r) {
            float mx = s[i][0][r];
            #pragma unroll
            for (int j = 1; j < 4; ++j) mx = fmaxf(mx, s[i][j][r]);
            #pragma unroll
            for (int d = 1; d < 16; d <<= 1) mx = fmaxf(mx, __shfl_xor(mx, d, 64));
            float sum = 0.f;
            #pragma unroll
            for (int j = 0; j < 4; ++j) {
                float p = __expf((s[i][j][r] - mx) * 0.125f);
                s[i][j][r] = p;
                sum += p;
            }
            #pragma unroll
            for (int d = 1; d < 16; d <<= 1) sum += __shfl_xor(sum, d, 64);
            rrec[i][r] = 1.f / sum;
        }
    }

    #pragma unroll
    for (int i = 0; i < 4; ++i)
        #pragma unroll
        for (int j = 0; j < 4; ++j)
            #pragma unroll
            for (int r = 0; r < 4; ++r) {
                const int row  = 16 * i + quad * 4 + r;
                const int col  = 16 * j + l16;
                const int slot = (col >> 3) ^ (row & 7);
                Kt[row * 64 + slot * 8 + (col & 7)] = (bf16)s[i][j][r];
            }
    __syncthreads();

    f32x4 o[4][4];
    #pragma unroll
    for (int i = 0; i < 4; ++i)
        #pragma unroll
        for (int j = 0; j < 4; ++j) o[i][j] = zero;

    #pragma unroll
    for (int ks = 0; ks < 2; ++ks) {
        bf16x8 pf[4], vf[4];
        #pragma unroll
        for (int i = 0; i < 4; ++i) {
            const int row  = 16 * i + l16;
            const int slot = (ks * 4 + quad) ^ (row & 7);
            pf[i] = *(const bf16x8*)(Kt + row * 64 + slot * 8);
        }
        #pragma unroll
        for (int j = 0; j < 4; ++j) {
            bf16x8 t;
            #pragma unroll
            for (int q = 0; q < 8; ++q)
                t[q] = Vt[(ks * 32 + quad * 8 + q) * 64 + 16 * j + l16];
            vf[j] = t;
        }
        #pragma unroll
        for (int i = 0; i < 4; ++i)
            #pragma unroll
            for (int j = 0; j < 4; ++j)
                o[i][j] = __builtin_amdgcn_mfma_f32_16x16x32_bf16(
                    pf[i], vf[j], o[i][j], 0, 0, 0);
    }

    #pragma unroll
    for (int i = 0; i < 4; ++i)
        #pragma unroll
        for (int j = 0; j < 4; ++j)
            #pragma unroll
            for (int r = 0; r < 4; ++r) {
                const size_t grow = rowbase + 16 * i + quad * 4 + r;
                const int col = h * 64 + 16 * j + l16;
                AOut[grow * 768 + col] = (bf16)(o[i][j][r] * rrec[i][r]);
            }
}

// ---------------------------------------------------------------------------
// Kernel 5: LN2 + fc1 (C->1) + exact gelu + fc2 (1->C). 1 wave per row.
// ---------------------------------------------------------------------------
__global__ __launch_bounds__(256)
void final_fused(const bf16* __restrict__ P, const float* __restrict__ g2,
                 const float* __restrict__ b2, const float* __restrict__ fc1w,
                 const float* __restrict__ fc1b, const float* __restrict__ fc2w,
                 const float* __restrict__ fc2b, float* __restrict__ out)
{
    const int row  = blockIdx.x * 4 + (threadIdx.x >> 6);
    const int lane = threadIdx.x & 63;
    const bf16* pr = P + (size_t)row * 768;
    float v[12];
    float sum = 0.f, ssq = 0.f;
    #pragma unroll
    for (int j = 0; j < 3; ++j) {
        bf16x4 c = *(const bf16x4*)(pr + j * 256 + lane * 4);
        #pragma unroll
        for (int q = 0; q < 4; ++q) {
            float f = (float)c[q];
            v[j * 4 + q] = f; sum += f; ssq += f * f;
        }
    }
    #pragma unroll
    for (int d = 1; d < 64; d <<= 1) {
        sum += __shfl_xor(sum, d, 64);
        ssq += __shfl_xor(ssq, d, 64);
    }
    const float mean = sum * (1.f / 768.f);
    const float rstd = rsqrtf(ssq * (1.f / 768.f) - mean * mean + 1e-5f);
    float part = 0.f;
    #pragma unroll
    for (int j = 0; j < 3; ++j) {
        const int c0 = j * 256 + lane * 4;
        f32x4 gg = *(const f32x4*)(g2 + c0);
        f32x4 bb = *(const f32x4*)(b2 + c0);
        f32x4 f1 = *(const f32x4*)(fc1w + c0);
        #pragma unroll
        for (int q = 0; q < 4; ++q) {
            float ln = (v[j * 4 + q] - mean) * rstd * gg[q] + bb[q];
            part += ln * f1[q];
        }
    }
    #pragma unroll
    for (int d = 1; d < 64; d <<= 1) part += __shfl_xor(part, d, 64);
    const float sv = part + fc1b[0];
    const float ge = 0.5f * sv * (1.f + erff(sv * 0.70710678118654752f));
    float* orow = out + (size_t)row * 768;
    #pragma unroll
    for (int j = 0; j < 3; ++j) {
        const int c0 = j * 256 + lane * 4;
        f32x4 f2  = *(const f32x4*)(fc2w + c0);
        f32x4 b2v = *(const f32x4*)(fc2b + c0);
        f32x4 ov;
        #pragma unroll
        for (int q = 0; q < 4; ++q)
            ov[q] = ge * f2[q] + b2v[q];
        *(f32x4*)(orow + c0) = ov;
    }
}

// ---------------------------------------------------------------------------
extern "C" void kernel_launch(void* const* d_in, const int* in_sizes, int n_in,
                              void* d_out, int out_size, void* d_ws, size_t ws_size,
                              hipStream_t stream)
{
    const float* x     = (const float*)d_in[0];
    const float* n1g   = (const float*)d_in[1];
    const float* n1b   = (const float*)d_in[2];
    const float* n2g   = (const float*)d_in[3];
    const float* n2b   = (const float*)d_in[4];
    const float* qkvw  = (const float*)d_in[5];
    const float* projw = (const float*)d_in[6];
    const float* projb = (const float*)d_in[7];
    const float* fc1w  = (const float*)d_in[8];
    const float* fc1b  = (const float*)d_in[9];
    const float* fc2w  = (const float*)d_in[10];
    const float* fc2b  = (const float*)d_in[11];
    float* out = (float*)d_out;

    const int total = in_sizes[0];          // B * 16384 * 768
    const int rows  = total / 768;          // 65536 token rows
    const int Smod  = total / 3;            // 2^24 for B=4
    const int Bw    = rows / 64;            // windows
    const int C     = 768;

    bf16* qkv     = (bf16*)d_ws;
    bf16* Ybuf    = qkv + (size_t)rows * 2304;
    bf16* qkvw_b  = Ybuf + (size_t)rows * 768;
    bf16* projw_b = qkvw_b + (size_t)3 * C * C;
    bf16* Pbuf    = qkv;

    const int nqkvw  = 3 * C * C;
    const int nprojw = C * C;
    f2b<<<(nqkvw / 4 + 255) / 256, 256, 0, stream>>>(qkvw, qkvw_b, nqkvw);
    f2b<<<(nprojw / 4 + 255) / 256, 256, 0, stream>>>(projw, projw_b, nprojw);

    ln1_win<<<rows / 4, 256, 0, stream>>>(x, n1g, n1b, Ybuf);

    const int nbm = rows / 128;             // 512
    gemm_bt<1, false><<<nbm * 9, 256, 0, stream>>>(
        nullptr, Ybuf, qkvw_b, nullptr, qkv, 768, 2304, Smod, 9);

    attn_win<<<Bw * 12, 64, 0, stream>>>(qkv, Ybuf);

    gemm_bt<0, true><<<nbm * 3, 256, 0, stream>>>(
        Ybuf, nullptr, projw_b, projb, Pbuf, 768, 768, 0, 3);

    final_fused<<<rows / 4, 256, 0, stream>>>(Pbuf, n2g, n2b, fc1w, fc1b,
                                              fc2w, fc2b, out);
}